// Round 7
// baseline (1464.774 us; speedup 1.0000x reference)
//
#include <hip/hip_runtime.h>
#include <cstdint>
#include <cstddef>

#define S_LEN 2048
#define HID   4096
#define INTER 11008
#define NHEADS 32
#define HD    128

typedef __attribute__((ext_vector_type(4))) float  f32x4;
typedef __attribute__((ext_vector_type(8))) __bf16 bf16x8;
typedef __attribute__((ext_vector_type(8))) short  s16x8;
typedef __attribute__((ext_vector_type(4))) short  s16x4;

__device__ __forceinline__ float bf2f(short s) {
  unsigned u = ((unsigned)(unsigned short)s) << 16;
  return __builtin_bit_cast(float, u);
}
__device__ __forceinline__ short f2bf(float f) {
  unsigned u = __builtin_bit_cast(unsigned, f);
  u += 0x7FFFu + ((u >> 16) & 1u);
  return (short)(u >> 16);
}
__device__ __forceinline__ f32x4 mfma16(s16x8 a, s16x8 b, f32x4 c) {
  return __builtin_amdgcn_mfma_f32_16x16x32_bf16(
      __builtin_bit_cast(bf16x8, a), __builtin_bit_cast(bf16x8, b), c, 0, 0, 0);
}
__device__ __forceinline__ void gload_lds16(const void* g, void* l) {
  __builtin_amdgcn_global_load_lds(
      (const __attribute__((address_space(1))) void*)g,
      (__attribute__((address_space(3))) void*)l, 16, 0, 0);
}

// ---------------- RMSNorm: f32 [2048][4096] -> bf16 ----------------
__global__ __launch_bounds__(256) void rmsnorm_kernel(const float* __restrict__ x,
                                                      const float* __restrict__ w,
                                                      short* __restrict__ out) {
  int row = blockIdx.x;
  const float* xr = x + (size_t)row * HID;
  short* orow = out + (size_t)row * HID;
  int tid = threadIdx.x;
  f32x4 v[4];
  float ss = 0.f;
#pragma unroll
  for (int i = 0; i < 4; ++i) {
    v[i] = ((const f32x4*)xr)[i * 256 + tid];
    ss += v[i][0] * v[i][0] + v[i][1] * v[i][1] + v[i][2] * v[i][2] + v[i][3] * v[i][3];
  }
#pragma unroll
  for (int off = 32; off > 0; off >>= 1) ss += __shfl_xor(ss, off);
  __shared__ float psum[4];
  if ((tid & 63) == 0) psum[tid >> 6] = ss;
  __syncthreads();
  float tot = psum[0] + psum[1] + psum[2] + psum[3];
  float r = rsqrtf(tot * (1.0f / (float)HID) + 1e-6f);
#pragma unroll
  for (int i = 0; i < 4; ++i) {
    int base = (i * 256 + tid) * 4;
    s16x4 o;
#pragma unroll
    for (int j = 0; j < 4; ++j) o[j] = f2bf(v[i][j] * r * w[base + j]);
    *(s16x4*)&orow[base] = o;
  }
}

// ---- one 64n x 64k GPTQ dequant tile, 512 threads, coalesced 16B stores ----
__device__ __forceinline__ void dq_tile(const int* __restrict__ qw, const int* __restrict__ qz,
                                        const float* __restrict__ sc, short* __restrict__ wt,
                                        int N, int noff, int dnx, int dqld, int tile, int tid) {
  int n0 = (tile % dnx) * 64;
  int k0 = (tile / dnx) * 64;
  int n = tid >> 3;        // 0..63
  int cc = tid & 7;        // 0..7 (8-elem k chunk)
  int gc = noff + n0 + n;
  int g = k0 >> 7;
  unsigned q = (unsigned)qw[(size_t)((k0 >> 3) + cc) * N + gc];
  float s = sc[(size_t)g * N + gc];
  unsigned zq = (unsigned)qz[(size_t)g * (N >> 3) + (gc >> 3)];
  float zs = ((float)((zq >> ((gc & 7) * 4)) & 15u) + 1.0f) * s;
  s16x8 o;
#pragma unroll
  for (int j = 0; j < 8; ++j)
    o[j] = f2bf(fmaf((float)((q >> (4 * j)) & 15u), s, -zs));
  *(s16x8*)&wt[(size_t)(n0 + n) * dqld + k0 + cc * 8] = o;
}

// ---------------- standalone dequant (for the first weights) ----------------
__global__ __launch_bounds__(512) void dq_kernel(const int* __restrict__ qw, const int* __restrict__ qz,
                                                 const float* __restrict__ sc, short* __restrict__ wt,
                                                 int N, int noff, int dnx, int dqld, int tpb) {
  for (int i = 0; i < tpb; ++i)
    dq_tile(qw, qz, sc, wt, N, noff, dnx, dqld, blockIdx.x * tpb + i, threadIdx.x);
}

// ------- 4-phase interleaved GEMM, BM=128 BN=256 BK=64, 8 waves (512 thr) -------
// C[M=2048][N] = A[M][lda] @ BT[N][ldb]^T. XOR-swizzled LDS (chunk^=(row&7)),
// counted vmcnt(3) at tile boundaries (loads stay in flight across barriers).
// omode: 0 bf16 store; 1 f32 base+acc; 2 f32 +=; 3 bf16 silu(C)*acc in place.
// Also carries dequant of NEXT weights (dqTiles spread across blocks, one tile
// per 4 K-steps). dq targets are ALWAYS disjoint from A/B/C (checked per launch).
__global__ __launch_bounds__(512, 1) void g256_kernel(
    const short* __restrict__ A, int lda, const short* __restrict__ BT, int ldb,
    void* __restrict__ Cv, int ldc, const float* __restrict__ base, int Kext,
    int gnx, int omode,
    const int* __restrict__ qw, const int* __restrict__ qz,
    const float* __restrict__ sc, short* __restrict__ wt,
    int dqN, int dqnoff, int dqnx, int dqld, int dqTiles) {
  __shared__ short As[2][128 * 64];   // 32 KB
  __shared__ short Bs[2][256 * 64];   // 64 KB
  int tid = threadIdx.x;
  int lane = tid & 63, wid = tid >> 6;
  int wr = wid >> 2, wc = wid & 3;    // wave tile: rows wr*64, cols wc*64
  int gtot = gnx * 16;
  int bid = blockIdx.x;
  int swz = (bid & 7) * (gtot >> 3) + (bid >> 3);
  int bn = swz % gnx, bm = swz / gnx;
  const short* Abase = A + (size_t)(bm * 128) * lda;
  const short* Bbase = BT + (size_t)(bn * 256) * ldb;
  int nk = Kext >> 6;

  int dqc = 0, dqe = 0;
  if (dqTiles > 0) {
    dqc = (int)((long)bid * dqTiles / gtot);
    dqe = (int)((long)(bid + 1) * dqTiles / gtot);
  }

  f32x4 acc[4][4] = {};

  // A-unit h: rows {h*32..+31} u {64+h*32..+31} (8KB, 1 load/thread)
  auto stageA = [&](int buf, int tt, int h) {
    if (tt >= nk) return;
    int rbase = (wid < 4 ? wid * 8 : 64 + (wid - 4) * 8) + h * 32;
    int row = rbase + (lane >> 3);
    int gcc = (lane & 7) ^ (row & 7);
    gload_lds16(Abase + (size_t)row * lda + tt * 64 + gcc * 8, &As[buf][rbase * 64]);
  };
  // B-unit h: rows {h*32 + 64*s, s=0..3} (16KB, 2 loads/thread)
  auto stageB = [&](int buf, int tt, int h) {
    if (tt >= nk) return;
#pragma unroll
    for (int seg = 0; seg < 2; ++seg) {
      int rbase = seg * 128 + (wid < 4 ? wid * 8 : 64 + (wid - 4) * 8) + h * 32;
      int row = rbase + (lane >> 3);
      int gcc = (lane & 7) ^ (row & 7);
      gload_lds16(Bbase + (size_t)row * ldb + tt * 64 + gcc * 8, &Bs[buf][rbase * 64]);
    }
  };
  auto lda_frag = [&](int buf, int mi, int ks) -> s16x8 {
    int row = wr * 64 + mi * 16 + (lane & 15);
    int cc = ks * 4 + (lane >> 4);
    return *(const s16x8*)&As[buf][row * 64 + ((cc ^ (row & 7)) * 8)];
  };
  auto ldb_frag = [&](int buf, int ni, int ks) -> s16x8 {
    int row = wc * 64 + ni * 16 + (lane & 15);
    int cc = ks * 4 + (lane >> 4);
    return *(const s16x8*)&Bs[buf][row * 64 + ((cc ^ (row & 7)) * 8)];
  };

  // prologue: tile0 fully, tile1 h0 units (issue order matters for vmcnt)
  stageA(0, 0, 0); stageB(0, 0, 0); stageA(0, 0, 1); stageB(0, 0, 1);
  stageA(1, 1, 0); stageB(1, 1, 0);
  asm volatile("s_waitcnt vmcnt(3)" ::: "memory");
  __builtin_amdgcn_s_barrier();
  __builtin_amdgcn_sched_barrier(0);

  for (int t = 0; t < nk; ++t) {
    int cb = t & 1, nb = cb ^ 1;
#pragma unroll
    for (int p = 0; p < 4; ++p) {
      // staged issues target regions whose last reader finished >=1 barrier ago
      if (p == 0) stageA(nb, t + 1, 1);
      else if (p == 1) stageB(nb, t + 1, 1);
      else if (p == 2) stageA(cb, t + 2, 0);
      else stageB(cb, t + 2, 0);
      const int mq = p >> 1, nq = p & 1;
      s16x8 af[2][2], bfr[2][2];
#pragma unroll
      for (int x = 0; x < 2; ++x)
#pragma unroll
        for (int ks = 0; ks < 2; ++ks) {
          af[x][ks] = lda_frag(cb, mq * 2 + x, ks);
          bfr[x][ks] = ldb_frag(cb, nq * 2 + x, ks);
        }
      __builtin_amdgcn_s_setprio(1);
#pragma unroll
      for (int x = 0; x < 2; ++x)
#pragma unroll
        for (int y = 0; y < 2; ++y)
#pragma unroll
          for (int ks = 0; ks < 2; ++ks)
            acc[mq * 2 + x][nq * 2 + y] =
                mfma16(af[x][ks], bfr[y][ks], acc[mq * 2 + x][nq * 2 + y]);
      __builtin_amdgcn_s_setprio(0);
      if (p == 3) {
        if (t + 2 < nk)      asm volatile("s_waitcnt vmcnt(3)" ::: "memory");
        else if (t + 1 < nk) asm volatile("s_waitcnt vmcnt(0)" ::: "memory");
      }
      __builtin_amdgcn_s_barrier();
      if (p == 3) __builtin_amdgcn_sched_barrier(0);
    }
    if ((t & 3) == 3 && dqc < dqe) {
      dq_tile(qw, qz, sc, wt, dqN, dqnoff, dqnx, dqld, dqc, tid);
      ++dqc;
    }
  }
  while (dqc < dqe) {
    dq_tile(qw, qz, sc, wt, dqN, dqnoff, dqnx, dqld, dqc, tid);
    ++dqc;
  }

  int row0 = bm * 128 + wr * 64 + ((lane >> 4) << 2);
  int col0 = bn * 256 + wc * 64 + (lane & 15);
#pragma unroll
  for (int mi = 0; mi < 4; ++mi)
#pragma unroll
    for (int ni = 0; ni < 4; ++ni)
#pragma unroll
      for (int j = 0; j < 4; ++j) {
        size_t idx = (size_t)(row0 + mi * 16 + j) * ldc + col0 + ni * 16;
        float a = acc[mi][ni][j];
        if (omode == 0)      ((short*)Cv)[idx] = f2bf(a);
        else if (omode == 1) ((float*)Cv)[idx] = base[idx] + a;
        else if (omode == 2) ((float*)Cv)[idx] = ((float*)Cv)[idx] + a;
        else {
          short* C = (short*)Cv;
          float g = bf2f(C[idx]);
          C[idx] = f2bf(g / (1.f + __expf(-g)) * a);
        }
      }
}

// ---------------- RoPE in-place on bf16 q,k (strided) ----------------
__global__ __launch_bounds__(128) void rope_kernel(short* __restrict__ q, int qld,
                                                   short* __restrict__ k, int kld,
                                                   const float* __restrict__ sp,
                                                   const float* __restrict__ cp) {
  int s = blockIdx.x, h = blockIdx.y;
  short* p = blockIdx.z ? (k + (size_t)s * kld + h * HD) : (q + (size_t)s * qld + h * HD);
  int d = threadIdx.x;
  float x = bf2f(p[d]);
  float xp = bf2f(p[d ^ 64]);
  float rot = (d < 64) ? -xp : xp;
  float y = x * cp[s * HD + d] + rot * sp[s * HD + d];
  __syncthreads();
  p[d] = f2bf(y);
}

// ---------------- Flash attention (causal), bf16 in/out, strided ----------------
// T14 async-STAGE prefetch; K and V^T XOR-swizzled LDS; (256,2): 2 blocks/CU
// with modest spills beats 1 block/CU spill-free (round-4 vs round-5 measured).
__global__ __launch_bounds__(256, 2) void attn_kernel(const short* __restrict__ qb, int qld,
                                                      const short* __restrict__ kb, int kld,
                                                      const short* __restrict__ vb, int vld,
                                                      short* __restrict__ ob) {
  int qt = (int)(gridDim.x - 1) - blockIdx.x;
  int h = blockIdx.y;
  int tid = threadIdx.x, lane = tid & 63, wv = tid >> 6;
  __shared__ short Kl[64 * 128];
  __shared__ short Vl[128 * 72];
  __shared__ short Pl[4][32 * 72];
  int q0 = qt * 128 + wv * 32;
  s16x8 qf[2][4];
#pragma unroll
  for (int m = 0; m < 2; ++m)
#pragma unroll
    for (int kf = 0; kf < 4; ++kf) {
      int r = q0 + m * 16 + (lane & 15);
      int d = kf * 32 + (lane >> 4) * 8;
      qf[m][kf] = *(const s16x8*)&qb[(size_t)r * qld + h * HD + d];
    }
  f32x4 o[2][8] = {};
  float mrow[2][4], lrow[2][4];
#pragma unroll
  for (int m = 0; m < 2; ++m)
#pragma unroll
    for (int j = 0; j < 4; ++j) { mrow[m][j] = -1e30f; lrow[m][j] = 0.f; }

  auto load_tile = [&](int kv0, s16x8* kr, s16x8* vr) {
#pragma unroll
    for (int i = 0; i < 4; ++i) {
      int cid = tid + i * 256;
      int kv = cid >> 4, c = cid & 15;
      kr[i] = *(const s16x8*)(kb + (size_t)(kv0 + kv) * kld + h * HD + c * 8);
      vr[i] = *(const s16x8*)(vb + (size_t)(kv0 + kv) * vld + h * HD + c * 8);
    }
  };
  auto store_tile = [&](const s16x8* kr, const s16x8* vr) {
#pragma unroll
    for (int i = 0; i < 4; ++i) {
      int cid = tid + i * 256;
      int kv = cid >> 4, c = cid & 15;
      *(s16x8*)((char*)Kl + kv * 256 + ((c ^ (kv & 7)) * 16)) = kr[i];
      int kvs = kv ^ ((c & 7) << 3);
#pragma unroll
      for (int j = 0; j < 8; ++j) Vl[(c * 8 + j) * 72 + kvs] = vr[i][j];
    }
  };

  const float scale = 0.08838834764831845f;
  int kv_end = qt * 128 + 128;
  s16x8 kra[4], vra[4], krb[4], vrb[4];
  load_tile(0, kra, vra);
  store_tile(kra, vra);
  __syncthreads();
  for (int kv0 = 0; kv0 < kv_end; kv0 += 64) {
    bool more = kv0 + 64 < kv_end;
    if (more) load_tile(kv0 + 64, krb, vrb);

    f32x4 sfr[2][4] = {};
    __builtin_amdgcn_s_setprio(1);
#pragma unroll
    for (int nf = 0; nf < 4; ++nf) {
      s16x8 kfr[4];
      int kvr = nf * 16 + (lane & 15);
#pragma unroll
      for (int kf = 0; kf < 4; ++kf) {
        int cc = (kf * 4 + (lane >> 4)) ^ (kvr & 7);
        kfr[kf] = *(const s16x8*)((const char*)Kl + kvr * 256 + cc * 16);
      }
#pragma unroll
      for (int m = 0; m < 2; ++m)
#pragma unroll
        for (int kf = 0; kf < 4; ++kf) sfr[m][nf] = mfma16(qf[m][kf], kfr[kf], sfr[m][nf]);
    }
    __builtin_amdgcn_s_setprio(0);
#pragma unroll
    for (int m = 0; m < 2; ++m)
#pragma unroll
      for (int j = 0; j < 4; ++j) {
        int qrow = q0 + m * 16 + (lane >> 4) * 4 + j;
        float pm = -1e30f;
#pragma unroll
        for (int nf = 0; nf < 4; ++nf) {
          int kvc = kv0 + nf * 16 + (lane & 15);
          float v = sfr[m][nf][j] * scale;
          v = (kvc <= qrow) ? v : -1e30f;
          sfr[m][nf][j] = v;
          pm = fmaxf(pm, v);
        }
#pragma unroll
        for (int off = 1; off < 16; off <<= 1) pm = fmaxf(pm, __shfl_xor(pm, off));
        float mnew = fmaxf(mrow[m][j], pm);
        float alpha = __expf(mrow[m][j] - mnew);
        mrow[m][j] = mnew;
        float rs = 0.f;
#pragma unroll
        for (int nf = 0; nf < 4; ++nf) {
          float pv = __expf(sfr[m][nf][j] - mnew);
          sfr[m][nf][j] = pv;
          rs += pv;
        }
#pragma unroll
        for (int off = 1; off < 16; off <<= 1) rs += __shfl_xor(rs, off);
        lrow[m][j] = lrow[m][j] * alpha + rs;
#pragma unroll
        for (int nd = 0; nd < 8; ++nd) o[m][nd][j] *= alpha;
      }
#pragma unroll
    for (int m = 0; m < 2; ++m)
#pragma unroll
      for (int nf = 0; nf < 4; ++nf)
#pragma unroll
        for (int j = 0; j < 4; ++j)
          Pl[wv][(m * 16 + (lane >> 4) * 4 + j) * 72 + nf * 16 + (lane & 15)] =
              f2bf(sfr[m][nf][j]);
    s16x8 pa[2][2];
#pragma unroll
    for (int m = 0; m < 2; ++m)
#pragma unroll
      for (int kf = 0; kf < 2; ++kf)
        pa[m][kf] = *(const s16x8*)&Pl[wv][(m * 16 + (lane & 15)) * 72 + kf * 32 + (lane >> 4) * 8];
    __builtin_amdgcn_s_setprio(1);
#pragma unroll
    for (int nd = 0; nd < 8; ++nd) {
      s16x8 vf[2];
      int drow = nd * 16 + (lane & 15);
      int key = ((drow >> 3) & 7) << 3;
#pragma unroll
      for (int kf = 0; kf < 2; ++kf)
        vf[kf] = *(const s16x8*)&Vl[drow * 72 + ((kf * 32 + (lane >> 4) * 8) ^ key)];
#pragma unroll
      for (int m = 0; m < 2; ++m)
#pragma unroll
        for (int kf = 0; kf < 2; ++kf) o[m][nd] = mfma16(pa[m][kf], vf[kf], o[m][nd]);
    }
    __builtin_amdgcn_s_setprio(0);
    __syncthreads();
    if (more) store_tile(krb, vrb);
    __syncthreads();
  }
#pragma unroll
  for (int m = 0; m < 2; ++m)
#pragma unroll
    for (int nd = 0; nd < 8; ++nd)
#pragma unroll
      for (int j = 0; j < 4; ++j) {
        int r = q0 + m * 16 + (lane >> 4) * 4 + j;
        int c = h * HD + nd * 16 + (lane & 15);
        ob[(size_t)r * HID + c] = f2bf(o[m][nd][j] / lrow[m][j]);
      }
}

extern "C" void kernel_launch(void* const* d_in, const int* in_sizes, int n_in,
                              void* d_out, int out_size, void* d_ws, size_t ws_size,
                              hipStream_t stream) {
  const int* qw[7]; const int* qz[7]; const float* sc[7];
  for (int i = 0; i < 7; ++i) {
    qw[i] = (const int*)d_in[i * 3 + 0];
    qz[i] = (const int*)d_in[i * 3 + 1];
    sc[i] = (const float*)d_in[i * 3 + 2];
  }
  const float* hin  = (const float*)d_in[21];
  const float* ln1  = (const float*)d_in[22];
  const float* ln2  = (const float*)d_in[23];
  const float* sinp = (const float*)d_in[24];
  const float* cosp = (const float*)d_in[25];
  float* out = (float*)d_out;   // holds h2 (f32) from o-proj onward

  char* ws = (char*)d_ws;
  const size_t MB = 1024 * 1024;
  // Layout (peak 128 MB; every launch's {A,B,C,dq-target} pairwise disjoint):
  short* XB  = (short*)(ws);              // [0,16): x1; then attn-out; then x2
  short* WA  = (short*)(ws + 16 * MB);    // [16,48): weight buf A (32 MB)
  short* WB  = (short*)(ws + 48 * MB);    // [48,80): weight buf B (32 MB)
  short* QB  = (short*)(ws + 80 * MB);    // [80,96): q; later gate/y chunk 0
  short* KBf = (short*)(ws + 96 * MB);    // [96,112): k; later chunk 1
  short* VBf = (short*)(ws + 112 * MB);   // [112,128): v; later chunk 2
  short* OB  = XB;                        // attn-out over dead x1
  short* G0 = QB; short* G1 = KBf; short* G2 = VBf;

  dim3 b512(512), b256(256);

  // x1 = rms(h, ln1)
  rmsnorm_kernel<<<S_LEN, b256, 0, stream>>>(hin, ln1, XB);
  // dq Wq -> WA
  dq_kernel<<<1024, b512, 0, stream>>>(qw[0], qz[0], sc[0], WA, HID, 0, 64, HID, 4);
  // q = x1@Wq -> QB ; dq Wk -> WB
  g256_kernel<<<256, b512, 0, stream>>>(XB, HID, WA, HID, QB, HID, nullptr, HID,
                                        16, 0, qw[1], qz[1], sc[1], WB, HID, 0, 64, HID, 4096);
  // k -> KBf ; dq Wv -> WA
  g256_kernel<<<256, b512, 0, stream>>>(XB, HID, WB, HID, KBf, HID, nullptr, HID,
                                        16, 0, qw[2], qz[2], sc[2], WA, HID, 0, 64, HID, 4096);
  // v -> VBf ; dq Wo -> WB
  g256_kernel<<<256, b512, 0, stream>>>(XB, HID, WA, HID, VBf, HID, nullptr, HID,
                                        16, 0, qw[3], qz[3], sc[3], WB, HID, 0, 64, HID, 4096);
  // rope, attention (attn-out -> OB over dead x1)
  rope_kernel<<<dim3(S_LEN, NHEADS, 2), dim3(128), 0, stream>>>(QB, HID, KBf, HID, sinp, cosp);
  attn_kernel<<<dim3(S_LEN / 128, NHEADS), b256, 0, stream>>>(QB, HID, KBf, HID, VBf, HID, OB);
  // h2 = h + o@Wo -> d_out ; dq Wg0 -> WA
  g256_kernel<<<256, b512, 0, stream>>>(OB, HID, WB, HID, out, HID, hin, HID,
                                        16, 1, qw[4], qz[4], sc[4], WA, INTER, 0, 64, HID, 4096);
  // x2 = rms(h2, ln2) -> XB (over dead attn-out)
  rmsnorm_kernel<<<S_LEN, b256, 0, stream>>>(out, ln2, XB);
  // ---- MLP chunk 0 (cols 0-4095), y in G0 ----
  g256_kernel<<<256, b512, 0, stream>>>(XB, HID, WA, HID, G0, HID, nullptr, HID,
                                        16, 0, qw[5], qz[5], sc[5], WB, INTER, 0, 64, HID, 4096);   // gate0 ; dq Wu0->WB
  g256_kernel<<<256, b512, 0, stream>>>(XB, HID, WB, HID, G0, HID, nullptr, HID,
                                        16, 3, qw[6], qz[6], sc[6], WA, HID, 0, 64, 4096, 4096);    // up0 silu-fuse ; dq Wd0->WA
  g256_kernel<<<256, b512, 0, stream>>>(G0, HID, WA, 4096, out, HID, nullptr, 4096,
                                        16, 2, qw[4], qz[4], sc[4], WB, INTER, 4096, 64, HID, 4096); // down0 ; dq Wg1->WB
  // ---- MLP chunk 1 (cols 4096-8191), y in G1 ----
  g256_kernel<<<256, b512, 0, stream>>>(XB, HID, WB, HID, G1, HID, nullptr, HID,
                                        16, 0, qw[5], qz[5], sc[5], WA, INTER, 4096, 64, HID, 4096); // gate1 ; dq Wu1->WA
  g256_kernel<<<256, b512, 0, stream>>>(XB, HID, WA, HID, G1, HID, nullptr, HID,
                                        16, 3, qw[6] + (size_t)(4096 >> 3) * HID,
                                        qz[6] + (size_t)(4096 >> 7) * (HID / 8),
                                        sc[6] + (size_t)(4096 >> 7) * HID,
                                        WB, HID, 0, 64, 4096, 4096);                                 // up1 ; dq Wd1->WB
  g256_kernel<<<256, b512, 0, stream>>>(G1, HID, WB, 4096, out, HID, nullptr, 4096,
                                        16, 2, qw[4], qz[4], sc[4], WA, INTER, 8192, 44, HID, 2816); // down1 ; dq Wg2->WA
  // ---- MLP chunk 2 (cols 8192-11007, N=2816), y in G2 ----
  g256_kernel<<<176, b512, 0, stream>>>(XB, HID, WA, HID, G2, HID, nullptr, HID,
                                        11, 0, qw[5], qz[5], sc[5], WB, INTER, 8192, 44, HID, 2816); // gate2 ; dq Wu2->WB
  g256_kernel<<<176, b512, 0, stream>>>(XB, HID, WB, HID, G2, HID, nullptr, HID,
                                        11, 3, qw[6] + (size_t)(8192 >> 3) * HID,
                                        qz[6] + (size_t)(8192 >> 7) * (HID / 8),
                                        sc[6] + (size_t)(8192 >> 7) * HID,
                                        WA, HID, 0, 64, 2816, 2816);                                 // up2 ; dq Wd2->WA
  g256_kernel<<<256, b512, 0, stream>>>(G2, HID, WA, 2816, out, HID, nullptr, 2816,
                                        16, 2, nullptr, nullptr, nullptr, nullptr, 0, 0, 1, 0, 0);   // down2
}

// Round 8
// 1386.279 us; speedup vs baseline: 1.0566x; 1.0566x over previous
//
#include <hip/hip_runtime.h>
#include <cstdint>
#include <cstddef>

#define S_LEN 2048
#define HID   4096
#define INTER 11008
#define NHEADS 32
#define HD    128

typedef __attribute__((ext_vector_type(4))) float  f32x4;
typedef __attribute__((ext_vector_type(8))) __bf16 bf16x8;
typedef __attribute__((ext_vector_type(8))) short  s16x8;
typedef __attribute__((ext_vector_type(4))) short  s16x4;

__device__ __forceinline__ float bf2f(short s) {
  unsigned u = ((unsigned)(unsigned short)s) << 16;
  return __builtin_bit_cast(float, u);
}
__device__ __forceinline__ short f2bf(float f) {
  unsigned u = __builtin_bit_cast(unsigned, f);
  u += 0x7FFFu + ((u >> 16) & 1u);
  return (short)(u >> 16);
}
__device__ __forceinline__ f32x4 mfma16(s16x8 a, s16x8 b, f32x4 c) {
  return __builtin_amdgcn_mfma_f32_16x16x32_bf16(
      __builtin_bit_cast(bf16x8, a), __builtin_bit_cast(bf16x8, b), c, 0, 0, 0);
}
__device__ __forceinline__ void gload_lds16(const void* g, void* l) {
  __builtin_amdgcn_global_load_lds(
      (const __attribute__((address_space(1))) void*)g,
      (__attribute__((address_space(3))) void*)l, 16, 0, 0);
}

// ---------------- RMSNorm: f32 [2048][4096] -> bf16 ----------------
__global__ __launch_bounds__(256) void rmsnorm_kernel(const float* __restrict__ x,
                                                      const float* __restrict__ w,
                                                      short* __restrict__ out) {
  int row = blockIdx.x;
  const float* xr = x + (size_t)row * HID;
  short* orow = out + (size_t)row * HID;
  int tid = threadIdx.x;
  f32x4 v[4];
  float ss = 0.f;
#pragma unroll
  for (int i = 0; i < 4; ++i) {
    v[i] = ((const f32x4*)xr)[i * 256 + tid];
    ss += v[i][0] * v[i][0] + v[i][1] * v[i][1] + v[i][2] * v[i][2] + v[i][3] * v[i][3];
  }
#pragma unroll
  for (int off = 32; off > 0; off >>= 1) ss += __shfl_xor(ss, off);
  __shared__ float psum[4];
  if ((tid & 63) == 0) psum[tid >> 6] = ss;
  __syncthreads();
  float tot = psum[0] + psum[1] + psum[2] + psum[3];
  float r = rsqrtf(tot * (1.0f / (float)HID) + 1e-6f);
#pragma unroll
  for (int i = 0; i < 4; ++i) {
    int base = (i * 256 + tid) * 4;
    s16x4 o;
#pragma unroll
    for (int j = 0; j < 4; ++j) o[j] = f2bf(v[i][j] * r * w[base + j]);
    *(s16x4*)&orow[base] = o;
  }
}

// -------- paired kernel: [0,gtot) = GEMM blocks, [gtot,..) = dequant blocks --------
// GEMM: C = A[M][lda] @ BT[128*gnx][ldb]^T, tiles 128x128, m97 structure, 32KB LDS
// so gemm blocks and dequant blocks co-reside on a CU (dq latency hidden).
//   OMODE 0: bf16 store; 1: f32 store base+acc; 2: f32 C += acc; 3: C=f2bf(silu(C)*acc)
template <int OMODE>
__global__ __launch_bounds__(256) void paired_kernel(
    const short* __restrict__ A, int lda,
    const short* __restrict__ BT, int ldb,
    void* __restrict__ Cv, int ldc,
    const float* __restrict__ base, int Kext,
    int gnx, int gny,
    const int* __restrict__ qw, const int* __restrict__ qz,
    const float* __restrict__ sc, short* __restrict__ wt,
    int N, int noff, int dnx, int dqld) {
  __shared__ short sm[4 * 4096];  // 32KB: As[2][4096] | Bs[2][4096]; dq reuses front
  int bid = blockIdx.x;
  int gtot = gnx * gny;
  int tid = threadIdx.x;
  if (bid < gtot) {
    // ---------------- GEMM ----------------
    int cpx = gtot >> 3;                       // gtot always %8==0 here
    int swz = (bid & 7) * cpx + (bid >> 3);    // XCD-contiguous chunks
    int bn = swz % gnx, bm = swz / gnx;
    int lane = tid & 63, wv = tid >> 6;
    int wr = wv >> 1, wc = wv & 1;
    f32x4 acc[4][4] = {};
    int nk = Kext >> 5;
    int lr = lane >> 2, lc = lane & 3;
    const short* Abase = A + (size_t)(bm * 128) * lda;
    const short* Bbase = BT + (size_t)(bn * 128) * ldb;
    short* As0 = sm;
    short* Bs0 = sm + 8192;

    auto stage = [&](int buf, int t) {
      int k0 = t << 5;
#pragma unroll
      for (int i = 0; i < 2; ++i) {
        int r = i * 64 + wv * 16 + lr;
        gload_lds16(Abase + (size_t)r * lda + k0 + lc * 8, As0 + buf * 4096 + i * 2048 + wv * 512);
        gload_lds16(Bbase + (size_t)r * ldb + k0 + lc * 8, Bs0 + buf * 4096 + i * 2048 + wv * 512);
      }
    };
    auto compute = [&](int buf) {
      int kc = (lane >> 4) * 8;
      int ra = wr * 64 + (lane & 15);
      int rb = wc * 64 + (lane & 15);
      s16x8 af[4], bfr[4];
#pragma unroll
      for (int m = 0; m < 4; ++m) af[m] = *(const s16x8*)&As0[buf * 4096 + (ra + m * 16) * 32 + kc];
#pragma unroll
      for (int n = 0; n < 4; ++n) bfr[n] = *(const s16x8*)&Bs0[buf * 4096 + (rb + n * 16) * 32 + kc];
#pragma unroll
      for (int m = 0; m < 4; ++m)
#pragma unroll
        for (int n = 0; n < 4; ++n) acc[m][n] = mfma16(af[m], bfr[n], acc[m][n]);
    };

    stage(0, 0);
    __syncthreads();
    for (int t = 0; t < nk; ++t) {
      if (t + 1 < nk) stage((t + 1) & 1, t + 1);
      compute(t & 1);
      __syncthreads();
    }

    int row0 = bm * 128 + wr * 64 + ((lane >> 4) << 2);
    int col0 = bn * 128 + wc * 64 + (lane & 15);
#pragma unroll
    for (int m = 0; m < 4; ++m)
#pragma unroll
      for (int n = 0; n < 4; ++n)
#pragma unroll
        for (int j = 0; j < 4; ++j) {
          size_t idx = (size_t)(row0 + m * 16 + j) * ldc + col0 + n * 16;
          if (OMODE == 0)      ((short*)Cv)[idx] = f2bf(acc[m][n][j]);
          else if (OMODE == 1) ((float*)Cv)[idx] = base[idx] + acc[m][n][j];
          else if (OMODE == 2) ((float*)Cv)[idx] = ((float*)Cv)[idx] + acc[m][n][j];
          else {  // silu(gate)*up, gate preloaded in Cv as bf16
            short* C = (short*)Cv;
            float g = bf2f(C[idx]);
            float sl = g / (1.f + __expf(-g));
            C[idx] = f2bf(sl * acc[m][n][j]);
          }
        }
  } else {
    // ---------------- dequant (co-resident with gemm blocks) ----------------
    int id = bid - gtot;
    int n0 = (id % dnx) * 64;
    int k0 = (id / dnx) * 64;
    int g = k0 >> 7;
    int qr0 = k0 >> 3;
#pragma unroll
    for (int i = 0; i < 2; ++i) {
      int idx = tid + i * 256;
      int r = idx >> 6;
      int n = idx & 63;
      int gc = noff + n0 + n;
      unsigned q = (unsigned)qw[(size_t)(qr0 + r) * N + gc];
      float s = sc[(size_t)g * N + gc];
      unsigned zq = (unsigned)qz[(size_t)g * (N >> 3) + (gc >> 3)];
      float zs = ((float)((zq >> ((gc & 7) * 4)) & 15u) + 1.0f) * s;
      s16x8 o;
#pragma unroll
      for (int j = 0; j < 8; ++j)
        o[j] = f2bf(fmaf((float)((q >> (4 * j)) & 15u), s, -zs));
      *(s16x8*)&sm[n * 72 + r * 8] = o;
    }
    __syncthreads();
    int n = tid >> 2;
#pragma unroll
    for (int i = 0; i < 2; ++i) {
      int c = (tid & 3) + i * 4;
      *(s16x8*)&wt[(size_t)(n0 + n) * dqld + k0 + c * 8] = *(const s16x8*)&sm[n * 72 + c * 8];
    }
  }
}

// ---------------- RoPE in-place on bf16 q,k ----------------
__global__ __launch_bounds__(128) void rope_kernel(short* __restrict__ q, short* __restrict__ k,
                                                   const float* __restrict__ sp,
                                                   const float* __restrict__ cp) {
  int s = blockIdx.x, h = blockIdx.y;
  short* p = (blockIdx.z ? k : q) + (size_t)s * HID + h * HD;
  int d = threadIdx.x;
  float x = bf2f(p[d]);
  float xp = bf2f(p[d ^ 64]);
  float rot = (d < 64) ? -xp : xp;
  float y = x * cp[s * HD + d] + rot * sp[s * HD + d];
  __syncthreads();
  p[d] = f2bf(y);
}

// ---------------- Flash attention (causal), bf16 in/out ----------------
// T14 async-STAGE prefetch; K and V^T XOR-swizzled LDS.
// (256,2): 2 blocks/CU with modest spills beats 1 block/CU spill-free
// (round-4 190us vs round-5 283us, same code otherwise).
__global__ __launch_bounds__(256, 2) void attn_kernel(const short* __restrict__ qb,
                                                      const short* __restrict__ kb,
                                                      const short* __restrict__ vb,
                                                      short* __restrict__ ob) {
  int qt = (int)(gridDim.x - 1) - blockIdx.x;  // descending work for packing
  int h = blockIdx.y;
  int tid = threadIdx.x, lane = tid & 63, wv = tid >> 6;
  __shared__ short Kl[64 * 128];     // [kv][d], 16B-chunk XOR-swizzled
  __shared__ short Vl[128 * 72];     // [d][kv] padded + XOR-swizzled
  __shared__ short Pl[4][32 * 72];   // per-wave [q][kv] padded
  int q0 = qt * 128 + wv * 32;
  s16x8 qf[2][4];
#pragma unroll
  for (int m = 0; m < 2; ++m)
#pragma unroll
    for (int kf = 0; kf < 4; ++kf) {
      int r = q0 + m * 16 + (lane & 15);
      int d = kf * 32 + (lane >> 4) * 8;
      qf[m][kf] = *(const s16x8*)&qb[(size_t)r * HID + h * HD + d];
    }
  f32x4 o[2][8] = {};
  float mrow[2][4], lrow[2][4];
#pragma unroll
  for (int m = 0; m < 2; ++m)
#pragma unroll
    for (int j = 0; j < 4; ++j) { mrow[m][j] = -1e30f; lrow[m][j] = 0.f; }

  auto load_tile = [&](int kv0, s16x8* kr, s16x8* vr) {
#pragma unroll
    for (int i = 0; i < 4; ++i) {
      int cid = tid + i * 256;
      int kv = cid >> 4, c = cid & 15;
      kr[i] = *(const s16x8*)(kb + (size_t)(kv0 + kv) * HID + h * HD + c * 8);
      vr[i] = *(const s16x8*)(vb + (size_t)(kv0 + kv) * HID + h * HD + c * 8);
    }
  };
  auto store_tile = [&](const s16x8* kr, const s16x8* vr) {
#pragma unroll
    for (int i = 0; i < 4; ++i) {
      int cid = tid + i * 256;
      int kv = cid >> 4, c = cid & 15;
      *(s16x8*)((char*)Kl + kv * 256 + ((c ^ (kv & 7)) * 16)) = kr[i];
      int kvs = kv ^ ((c & 7) << 3);
#pragma unroll
      for (int j = 0; j < 8; ++j) Vl[(c * 8 + j) * 72 + kvs] = vr[i][j];
    }
  };

  const float scale = 0.08838834764831845f;
  int kv_end = qt * 128 + 128;
  s16x8 kra[4], vra[4], krb[4], vrb[4];
  load_tile(0, kra, vra);
  store_tile(kra, vra);
  __syncthreads();
  for (int kv0 = 0; kv0 < kv_end; kv0 += 64) {
    bool more = kv0 + 64 < kv_end;
    if (more) load_tile(kv0 + 64, krb, vrb);   // prefetch under compute

    f32x4 sfr[2][4] = {};
    __builtin_amdgcn_s_setprio(1);
#pragma unroll
    for (int nf = 0; nf < 4; ++nf) {
      s16x8 kfr[4];
      int kvr = nf * 16 + (lane & 15);
#pragma unroll
      for (int kf = 0; kf < 4; ++kf) {
        int cc = (kf * 4 + (lane >> 4)) ^ (kvr & 7);
        kfr[kf] = *(const s16x8*)((const char*)Kl + kvr * 256 + cc * 16);
      }
#pragma unroll
      for (int m = 0; m < 2; ++m)
#pragma unroll
        for (int kf = 0; kf < 4; ++kf) sfr[m][nf] = mfma16(qf[m][kf], kfr[kf], sfr[m][nf]);
    }
    __builtin_amdgcn_s_setprio(0);
#pragma unroll
    for (int m = 0; m < 2; ++m)
#pragma unroll
      for (int j = 0; j < 4; ++j) {
        int qrow = q0 + m * 16 + (lane >> 4) * 4 + j;
        float pm = -1e30f;
#pragma unroll
        for (int nf = 0; nf < 4; ++nf) {
          int kvc = kv0 + nf * 16 + (lane & 15);
          float v = sfr[m][nf][j] * scale;
          v = (kvc <= qrow) ? v : -1e30f;
          sfr[m][nf][j] = v;
          pm = fmaxf(pm, v);
        }
#pragma unroll
        for (int off = 1; off < 16; off <<= 1) pm = fmaxf(pm, __shfl_xor(pm, off));
        float mnew = fmaxf(mrow[m][j], pm);
        float alpha = __expf(mrow[m][j] - mnew);
        mrow[m][j] = mnew;
        float rs = 0.f;
#pragma unroll
        for (int nf = 0; nf < 4; ++nf) {
          float pv = __expf(sfr[m][nf][j] - mnew);
          sfr[m][nf][j] = pv;
          rs += pv;
        }
#pragma unroll
        for (int off = 1; off < 16; off <<= 1) rs += __shfl_xor(rs, off);
        lrow[m][j] = lrow[m][j] * alpha + rs;
#pragma unroll
        for (int nd = 0; nd < 8; ++nd) o[m][nd][j] *= alpha;
      }
#pragma unroll
    for (int m = 0; m < 2; ++m)
#pragma unroll
      for (int nf = 0; nf < 4; ++nf)
#pragma unroll
        for (int j = 0; j < 4; ++j)
          Pl[wv][(m * 16 + (lane >> 4) * 4 + j) * 72 + nf * 16 + (lane & 15)] =
              f2bf(sfr[m][nf][j]);
    s16x8 pa[2][2];
#pragma unroll
    for (int m = 0; m < 2; ++m)
#pragma unroll
      for (int kf = 0; kf < 2; ++kf)
        pa[m][kf] = *(const s16x8*)&Pl[wv][(m * 16 + (lane & 15)) * 72 + kf * 32 + (lane >> 4) * 8];
    __builtin_amdgcn_s_setprio(1);
#pragma unroll
    for (int nd = 0; nd < 8; ++nd) {
      s16x8 vf[2];
      int drow = nd * 16 + (lane & 15);
      int key = ((drow >> 3) & 7) << 3;
#pragma unroll
      for (int kf = 0; kf < 2; ++kf)
        vf[kf] = *(const s16x8*)&Vl[drow * 72 + ((kf * 32 + (lane >> 4) * 8) ^ key)];
#pragma unroll
      for (int m = 0; m < 2; ++m)
#pragma unroll
        for (int kf = 0; kf < 2; ++kf) o[m][nd] = mfma16(pa[m][kf], vf[kf], o[m][nd]);
    }
    __builtin_amdgcn_s_setprio(0);
    __syncthreads();                 // all waves done reading Kl/Vl
    if (more) store_tile(krb, vrb);  // write prefetched tile
    __syncthreads();
  }
#pragma unroll
  for (int m = 0; m < 2; ++m)
#pragma unroll
    for (int nd = 0; nd < 8; ++nd)
#pragma unroll
      for (int j = 0; j < 4; ++j) {
        int r = q0 + m * 16 + (lane >> 4) * 4 + j;
        int c = h * HD + nd * 16 + (lane & 15);
        ob[(size_t)r * HID + c] = f2bf(o[m][nd][j] / lrow[m][j]);
      }
}

extern "C" void kernel_launch(void* const* d_in, const int* in_sizes, int n_in,
                              void* d_out, int out_size, void* d_ws, size_t ws_size,
                              hipStream_t stream) {
  const int* qw[7]; const int* qz[7]; const float* sc[7];
  for (int i = 0; i < 7; ++i) {
    qw[i] = (const int*)d_in[i * 3 + 0];
    qz[i] = (const int*)d_in[i * 3 + 1];
    sc[i] = (const float*)d_in[i * 3 + 2];
  }
  const float* hin  = (const float*)d_in[21];
  const float* ln1  = (const float*)d_in[22];
  const float* ln2  = (const float*)d_in[23];
  const float* sinp = (const float*)d_in[24];
  const float* cosp = (const float*)d_in[25];
  float* out = (float*)d_out;        // h2 lives here from o-proj onward

  char* ws = (char*)d_ws;
  const size_t MB = 1024 * 1024;
  // peak ws usage: 128 MB (proven-safe)
  short* XB    = (short*)(ws);              // [0,16)  x1 then x2, bf16
  short* WA    = (short*)(ws + 16 * MB);    // [16,48)  weight buf A (32MB)
  short* WB    = (short*)(ws + 48 * MB);    // [48,80)  weight buf B (32MB)
  short* KB    = (short*)(ws + 80 * MB);    // [80,96)
  short* VB    = (short*)(ws + 96 * MB);    // [96,112)
  short* OB    = (short*)(ws + 112 * MB);   // [112,128)
  short* GATEB = (short*)(ws + 80 * MB);    // [80,123) aliases KB/VB/OB after attn
  short* UPB   = XB;                        // not used; kept for clarity
  (void)UPB;
  short* QBd   = (short*)d_out;             // q bf16 in d_out[0:16MB) (dead until o-proj)

  dim3 blk(256);
  const int noffs[3] = {0, 4096, 8192};
  const int nexts[3] = {4096, 4096, 2816};

  // L0: x1 = rms(h, ln1)
  rmsnorm_kernel<<<S_LEN, blk, 0, stream>>>(hin, ln1, XB);
  // L1: dequant Wq -> WA (pure dequant launch)
  paired_kernel<0><<<4096, blk, 0, stream>>>(nullptr, 0, nullptr, 0, nullptr, 0, nullptr, 0,
                                             0, 0, qw[0], qz[0], sc[0], WA, HID, 0, 64, HID);
  // L2: q = x1@Wq -> QBd  || dequant Wk -> WB
  paired_kernel<0><<<512 + 4096, blk, 0, stream>>>(XB, HID, WA, HID, QBd, HID, nullptr, HID,
                                                   32, 16, qw[1], qz[1], sc[1], WB, HID, 0, 64, HID);
  // L3: k -> KB || dequant Wv -> WA
  paired_kernel<0><<<512 + 4096, blk, 0, stream>>>(XB, HID, WB, HID, KB, HID, nullptr, HID,
                                                   32, 16, qw[2], qz[2], sc[2], WA, HID, 0, 64, HID);
  // L4: v -> VB || dequant Wo -> WB
  paired_kernel<0><<<512 + 4096, blk, 0, stream>>>(XB, HID, WA, HID, VB, HID, nullptr, HID,
                                                   32, 16, qw[3], qz[3], sc[3], WB, HID, 0, 64, HID);
  // L5/L6: rope + attention
  rope_kernel<<<dim3(S_LEN, NHEADS, 2), dim3(128), 0, stream>>>(QBd, KB, sinp, cosp);
  attn_kernel<<<dim3(S_LEN / 128, NHEADS), blk, 0, stream>>>(QBd, KB, VB, OB);
  // L7: h2 = h + o@Wo -> d_out || dequant gate_c0 -> WA
  paired_kernel<1><<<512 + 4096, blk, 0, stream>>>(OB, HID, WB, HID, out, HID, hin, HID,
                                                   32, 16, qw[4], qz[4], sc[4], WA, INTER, 0, 64, HID);
  // L8: x2 = rms(h2, ln2)
  rmsnorm_kernel<<<S_LEN, blk, 0, stream>>>(out, ln2, XB);

  // MLP: per chunk c: gate_c (OMODE0) then up_c (OMODE3: y=silu(gate)*up in place),
  // each paired with the next dequant. Buffers alternate WA/WB strictly.
  // L9:  gate_c0 (WA) || dq up_c0 -> WB
  paired_kernel<0><<<512 + 4096, blk, 0, stream>>>(XB, HID, WA, HID, GATEB + 0, INTER, nullptr, HID,
                                                   32, 16, qw[5], qz[5], sc[5], WB, INTER, 0, 64, HID);
  // L10: up_c0 (WB) || dq gate_c1 -> WA
  paired_kernel<3><<<512 + 4096, blk, 0, stream>>>(XB, HID, WB, HID, GATEB + 0, INTER, nullptr, HID,
                                                   32, 16, qw[4], qz[4], sc[4], WA, INTER, 4096, 64, HID);
  // L11: gate_c1 (WA) || dq up_c1 -> WB
  paired_kernel<0><<<512 + 4096, blk, 0, stream>>>(XB, HID, WA, HID, GATEB + 4096, INTER, nullptr, HID,
                                                   32, 16, qw[5], qz[5], sc[5], WB, INTER, 4096, 64, HID);
  // L12: up_c1 (WB) || dq gate_c2 -> WA (2816 cols -> 44x64 blocks)
  paired_kernel<3><<<512 + 2816, blk, 0, stream>>>(XB, HID, WB, HID, GATEB + 4096, INTER, nullptr, HID,
                                                   32, 16, qw[4], qz[4], sc[4], WA, INTER, 8192, 44, HID);
  // L13: gate_c2 (WA, gnx=22) || dq up_c2 -> WB
  paired_kernel<0><<<352 + 2816, blk, 0, stream>>>(XB, HID, WA, HID, GATEB + 8192, INTER, nullptr, HID,
                                                   22, 16, qw[5], qz[5], sc[5], WB, INTER, 8192, 44, HID);
  // L14: up_c2 (WB, gnx=22) || dq down_c0 -> WA
  paired_kernel<3><<<352 + 4096, blk, 0, stream>>>(XB, HID, WB, HID, GATEB + 8192, INTER, nullptr, HID,
                                                   22, 16, qw[6], qz[6], sc[6], WA, HID, 0, 64, 4096);
  // L15: down_c0: out += y[:,0:4096]@Wd0 (WA) || dq down_c1 -> WB
  paired_kernel<2><<<512 + 4096, blk, 0, stream>>>(GATEB + 0, INTER, WA, 4096, out, HID, nullptr, 4096,
                                                   32, 16,
                                                   qw[6] + (size_t)(4096 >> 3) * HID,
                                                   qz[6] + (size_t)(4096 >> 7) * (HID / 8),
                                                   sc[6] + (size_t)(4096 >> 7) * HID,
                                                   WB, HID, 0, 64, 4096);
  // L16: down_c1 (WB) || dq down_c2 -> WA (2816 k -> 64x44 blocks)
  paired_kernel<2><<<512 + 2816, blk, 0, stream>>>(GATEB + 4096, INTER, WB, 4096, out, HID, nullptr, 4096,
                                                   32, 16,
                                                   qw[6] + (size_t)(8192 >> 3) * HID,
                                                   qz[6] + (size_t)(8192 >> 7) * (HID / 8),
                                                   sc[6] + (size_t)(8192 >> 7) * HID,
                                                   WA, HID, 0, 64, 2816);
  // L17: down_c2 (WA, Kext=2816), pure gemm
  paired_kernel<2><<<512, blk, 0, stream>>>(GATEB + 8192, INTER, WA, 2816, out, HID, nullptr, 2816,
                                            32, 16, nullptr, nullptr, nullptr, nullptr, HID, 0, 1, HID);
}